// Round 1
// 5287.684 us; speedup vs baseline: 1.2572x; 1.2572x over previous
//
#include <hip/hip_runtime.h>
#include <math.h>

// N=4, L=S=4096, C=256, K=100, NHEAD=8, D=32. FP32 I/O.
// Big GEMMs: bf16x3 split MFMA (hi*hi + hi*lo + lo*hi, fp32 acc) ~ fp32 fidelity.
// Sample loop batched into 48 packed segments (6 samples x 8 batch-halves),
// 128-aligned inside an [8][4864]-row arena.
// LN fused into GEMM epilogues (gemm256: full 256-col row per block).
// R1: weights stored as 256-col groups of K-panels [k/32][n&255][32] so a
//     block's B tile per k-step is one contiguous 16KB run (coalesced loads,
//     was 64-distinct-lines-per-wave-load), and depth-1 register prefetch of
//     next k-panel's A+B overlaps global latency with the MFMA phase
//     (top sites run ~50 blocks = 1 wave/SIMD: zero TLP, ILP must hide latency).

typedef __attribute__((ext_vector_type(8))) short short8;
typedef __attribute__((ext_vector_type(4))) short s4;
typedef __attribute__((ext_vector_type(4))) float f32x4;

#define ARENA 4864  // rows per g in packed arena (4096 + 6*128 alignment pad)

__device__ __forceinline__ short f2bf(float f) {
  unsigned u = __float_as_uint(f);
  return (short)((u + 0x7FFFu + ((u >> 16) & 1u)) >> 16);
}
__device__ __forceinline__ float bf2f(short s) {
  return __uint_as_float(((unsigned)(unsigned short)s) << 16);
}

// ---------------------------------------------------------------------------
// Weight prep: per layer L, panel-major bf16 hi/lo planes.
// Layout per matrix: 256-col groups; group g holds cols [g*256,(g+1)*256);
// within group: panel p = k/32 (8192 shorts each); within panel: (n&255)*32+(k&31).
// Per-layer stride 1310720 shorts:
//   +0       QKV [768][256] hi (Wq group0, Wk group1, Wv group2), lo +196608
//   +393216  Wm  [256][256] hi, lo +65536
//   +524288  W1  [512][512] hi (2 groups of 131072), lo +262144
//   +1048576 W2  [256][512] hi, lo +131072
// ---------------------------------------------------------------------------
__global__ void prep_w_kernel(const float* __restrict__ Wq, const float* __restrict__ Wk,
                              const float* __restrict__ Wv, const float* __restrict__ Wm,
                              const float* __restrict__ W1, const float* __restrict__ W2,
                              short* __restrict__ wb) {
  long i = (long)blockIdx.x * 256 + threadIdx.x;
  if (i >= 8L * 655360) return;
  int L = (int)(i / 655360);
  int r = (int)(i % 655360);
  long base = (long)L * 1310720;
  float v; long dhi; int loD;
  if (r < 196608) {
    int n = r >> 8, k = r & 255;
    const float* s = (n < 256) ? (Wq + (long)L * 65536)
                   : (n < 512) ? (Wk + (long)L * 65536) : (Wv + (long)L * 65536);
    v = s[k * 256 + (n & 255)];
    dhi = base + ((long)(n >> 8) << 16) + ((long)(k >> 5) << 13) + ((n & 255) << 5) + (k & 31);
    loD = 196608;
  } else if (r < 262144) {
    int j = r - 196608; int n = j >> 8, k = j & 255;
    v = Wm[(long)L * 65536 + k * 256 + n];
    dhi = base + 393216 + ((long)(k >> 5) << 13) + (n << 5) + (k & 31);
    loD = 65536;
  } else if (r < 524288) {
    int j = r - 262144; int n = j >> 9, k = j & 511;
    v = W1[(long)L * 262144 + (long)k * 512 + n];
    dhi = base + 524288 + ((long)(n >> 8) << 17) + ((long)(k >> 5) << 13) + ((n & 255) << 5) + (k & 31);
    loD = 262144;
  } else {
    int j = r - 524288; int n = j >> 9, k = j & 511;
    v = W2[(long)L * 131072 + (long)k * 256 + n];
    dhi = base + 1048576 + ((long)(k >> 5) << 13) + (n << 5) + (k & 31);
    loD = 131072;
  }
  short h = f2bf(v);
  wb[dhi] = h;
  wb[dhi + loD] = f2bf(v - bf2f(h));
}

// ---------------------------------------------------------------------------
// gemm_main: 128x128 tiles, plain-batch OR packed-segment addressing,
// up to 3 column-routed outputs, optional dual A ([x | A2] for h1).
// modes: 0 none, 1 relu, 2 elu(x)+1. Panel-layout B + depth-1 prefetch.
// ---------------------------------------------------------------------------
__global__ __launch_bounds__(256) void gemm_main_kernel(
    const float* __restrict__ A, const float* __restrict__ A2, int aw,
    const short* __restrict__ Bh, int loD,
    float* __restrict__ C0, float* __restrict__ C1, float* __restrict__ C2,
    int M, int Kd, int outW, long sA, long sC,
    const int* __restrict__ cnt, int bmask, int bxor,
    const int* __restrict__ segOff, const int* __restrict__ segCnt, int gmin, int gmax,
    int mode0, int mode1, int mode2)
{
  int z = blockIdx.z;
  long aBase, cBase; int cntb;
  if (segOff) {
    int g = z & 7;
    if (g < gmin || g > gmax) return;
    long rb = (long)g * ARENA + segOff[z];
    aBase = rb * aw; cBase = rb * (long)outW;
    cntb = segCnt[z];
  } else {
    int ab = (z & bmask) ^ bxor;
    aBase = (long)ab * sA; cBase = (long)z * sC;
    cntb = cnt ? min(cnt[ab], M) : M;
  }
  int row0 = blockIdx.y * 128;
  if (row0 >= cntb) return;
  int colg = blockIdx.x * 128;
  int sel = colg / outW;
  float* Cb = (sel == 0 ? C0 : (sel == 1 ? C1 : C2)) + cBase;
  int mode = (sel == 0 ? mode0 : (sel == 1 ? mode1 : mode2));
  int colo = colg % outW;

  int t = threadIdx.x;
  int lane = t & 63, wid = t >> 6, wm = wid >> 1, wn = wid & 1;
  int fi = lane & 15, fq = lane >> 4;

  __shared__ __align__(16) short Ah[128][36];
  __shared__ __align__(16) short Al[128][36];
  __shared__ __align__(16) short Bsh[128][36];
  __shared__ __align__(16) short Bsl[128][36];

  f32x4 acc[4][4];
  #pragma unroll
  for (int i = 0; i < 4; i++)
    #pragma unroll
    for (int j = 0; j < 4; j++)
      acc[i][j] = (f32x4){0.f, 0.f, 0.f, 0.f};

  int tr = t >> 3, tc = (t & 7) * 4;
  int nc = t >> 1, kh = (t & 1) * 16;
  int gb = colg >> 8;
  int cg = (colg & 255) + nc;
  const short* bBase = Bh + (long)gb * ((long)Kd << 8) + (long)cg * 32 + kh;

  float4 avp[4];
  short8 bhp[2], blp[2];

  auto issueA = [&](int k0) {
    bool useA2 = (A2 != nullptr) && (k0 >= 256);
    const float* Asrc = useA2 ? A2 : A;
    int kcol = useA2 ? (k0 - 256) : k0;
    #pragma unroll
    for (int p = 0; p < 4; p++) {
      int gr = row0 + tr + p * 32;
      avp[p] = make_float4(0.f, 0.f, 0.f, 0.f);
      if (gr < M) avp[p] = *(const float4*)&Asrc[aBase + (long)gr * aw + kcol + tc];
    }
  };
  auto issueB = [&](int k0) {
    const short* bs = bBase + ((long)(k0 >> 5) << 13);
    bhp[0] = *(const short8*)bs;
    bhp[1] = *(const short8*)(bs + 8);
    blp[0] = *(const short8*)(bs + loD);
    blp[1] = *(const short8*)(bs + loD + 8);
  };

  issueA(0); issueB(0);
  for (int k0 = 0; k0 < Kd; k0 += 32) {
    #pragma unroll
    for (int p = 0; p < 4; p++) {
      float vv[4] = {avp[p].x, avp[p].y, avp[p].z, avp[p].w};
      s4 h4, l4;
      #pragma unroll
      for (int e = 0; e < 4; e++) {
        short h = f2bf(vv[e]); h4[e] = h; l4[e] = f2bf(vv[e] - bf2f(h));
      }
      *(s4*)&Ah[tr + p * 32][tc] = h4;
      *(s4*)&Al[tr + p * 32][tc] = l4;
    }
    *(short8*)&Bsh[nc][kh]     = bhp[0];
    *(short8*)&Bsh[nc][kh + 8] = bhp[1];
    *(short8*)&Bsl[nc][kh]     = blp[0];
    *(short8*)&Bsl[nc][kh + 8] = blp[1];
    if (k0 + 32 < Kd) { issueA(k0 + 32); issueB(k0 + 32); }
    __syncthreads();
    short8 ah[4], al[4], bh[4], bl[4];
    #pragma unroll
    for (int i = 0; i < 4; i++) {
      ah[i] = *(const short8*)&Ah[wm * 64 + i * 16 + fi][fq * 8];
      al[i] = *(const short8*)&Al[wm * 64 + i * 16 + fi][fq * 8];
    }
    #pragma unroll
    for (int j = 0; j < 4; j++) {
      bh[j] = *(const short8*)&Bsh[wn * 64 + j * 16 + fi][fq * 8];
      bl[j] = *(const short8*)&Bsl[wn * 64 + j * 16 + fi][fq * 8];
    }
    #pragma unroll
    for (int i = 0; i < 4; i++)
      #pragma unroll
      for (int j = 0; j < 4; j++) {
        acc[i][j] = __builtin_amdgcn_mfma_f32_16x16x32_bf16(ah[i], bh[j], acc[i][j], 0, 0, 0);
        acc[i][j] = __builtin_amdgcn_mfma_f32_16x16x32_bf16(ah[i], bl[j], acc[i][j], 0, 0, 0);
        acc[i][j] = __builtin_amdgcn_mfma_f32_16x16x32_bf16(al[i], bh[j], acc[i][j], 0, 0, 0);
      }
    __syncthreads();
  }
  #pragma unroll
  for (int i = 0; i < 4; i++) {
    #pragma unroll
    for (int reg = 0; reg < 4; reg++) {
      int gr = row0 + wm * 64 + i * 16 + fq * 4 + reg;
      if (gr >= M || gr >= cntb) continue;
      #pragma unroll
      for (int j = 0; j < 4; j++) {
        int cc = colo + wn * 64 + j * 16 + fi;
        float v = acc[i][j][reg];
        if (mode == 1) { if (v < 0.f) v = 0.f; }
        else if (mode == 2) { v = (v > 0.f) ? (v + 1.f) : expf(v); }
        Cb[(long)gr * outW + cc] = v;
      }
    }
  }
}

// ---------------------------------------------------------------------------
// gemm256: N=256 exactly, 128x256 tile per block (full output row), plain or
// packed addressing. modes: 0 none, 2 elu+1, 3 LN->C, 4 X += LN (h2+residual).
// Panel-layout B + depth-1 prefetch.
// ---------------------------------------------------------------------------
__global__ __launch_bounds__(256) void gemm256_kernel(
    const float* __restrict__ A, int aw, const short* __restrict__ Bh, int loD,
    float* __restrict__ C, float* __restrict__ X,
    int M, int Kd, long sA, long sC, long sX,
    const int* __restrict__ cnt, int bmask, int bxor,
    const int* __restrict__ segOff, const int* __restrict__ segCnt, int gmin, int gmax,
    int mode)
{
  int z = blockIdx.z;
  long aBase, cBase, xBase; int cntb;
  if (segOff) {
    int g = z & 7;
    if (g < gmin || g > gmax) return;
    long rb = (long)g * ARENA + segOff[z];
    aBase = rb * aw; cBase = rb * 256; xBase = rb * 256;
    cntb = segCnt[z];
  } else {
    int ab = (z & bmask) ^ bxor;
    aBase = (long)ab * sA; cBase = (long)z * sC; xBase = (long)ab * sX;
    cntb = cnt ? min(cnt[ab], M) : M;
  }
  int row0 = blockIdx.y * 128;
  if (row0 >= cntb) return;

  int t = threadIdx.x;
  int lane = t & 63, wid = t >> 6, wm = wid >> 1, wn = wid & 1;
  int fi = lane & 15, fq = lane >> 4;

  __shared__ __align__(16) short Ah[128][36];
  __shared__ __align__(16) short Al[128][36];
  __shared__ __align__(16) short Bsh[256][36];
  __shared__ __align__(16) short Bsl[256][36];
  __shared__ float lnS[2][128];
  __shared__ float lnQ[2][128];
  __shared__ float muS[128];
  __shared__ float rsS[128];

  f32x4 acc[4][8];
  #pragma unroll
  for (int i = 0; i < 4; i++)
    #pragma unroll
    for (int j = 0; j < 8; j++)
      acc[i][j] = (f32x4){0.f, 0.f, 0.f, 0.f};

  int tr = t >> 3, tc = (t & 7) * 4;
  const short* bBase = Bh + (long)t * 32;

  float4 avp[4];
  short8 bhp[4], blp[4];

  auto issueA = [&](int k0) {
    #pragma unroll
    for (int p = 0; p < 4; p++) {
      int gr = row0 + tr + p * 32;
      avp[p] = make_float4(0.f, 0.f, 0.f, 0.f);
      if (gr < M) avp[p] = *(const float4*)&A[aBase + (long)gr * aw + k0 + tc];
    }
  };
  auto issueB = [&](int k0) {
    const short* bs = bBase + ((long)(k0 >> 5) << 13);
    #pragma unroll
    for (int q = 0; q < 4; q++) {
      bhp[q] = *(const short8*)(bs + q * 8);
      blp[q] = *(const short8*)(bs + loD + q * 8);
    }
  };

  issueA(0); issueB(0);
  for (int k0 = 0; k0 < Kd; k0 += 32) {
    #pragma unroll
    for (int p = 0; p < 4; p++) {
      float vv[4] = {avp[p].x, avp[p].y, avp[p].z, avp[p].w};
      s4 h4, l4;
      #pragma unroll
      for (int e = 0; e < 4; e++) {
        short h = f2bf(vv[e]); h4[e] = h; l4[e] = f2bf(vv[e] - bf2f(h));
      }
      *(s4*)&Ah[tr + p * 32][tc] = h4;
      *(s4*)&Al[tr + p * 32][tc] = l4;
    }
    #pragma unroll
    for (int q = 0; q < 4; q++) {
      *(short8*)&Bsh[t][q * 8] = bhp[q];
      *(short8*)&Bsl[t][q * 8] = blp[q];
    }
    if (k0 + 32 < Kd) { issueA(k0 + 32); issueB(k0 + 32); }
    __syncthreads();
    short8 ah[4], al[4];
    #pragma unroll
    for (int i = 0; i < 4; i++) {
      ah[i] = *(const short8*)&Ah[wm * 64 + i * 16 + fi][fq * 8];
      al[i] = *(const short8*)&Al[wm * 64 + i * 16 + fi][fq * 8];
    }
    #pragma unroll
    for (int jh = 0; jh < 2; jh++) {
      short8 bh[4], bl[4];
      #pragma unroll
      for (int j = 0; j < 4; j++) {
        bh[j] = *(const short8*)&Bsh[wn * 128 + (jh * 4 + j) * 16 + fi][fq * 8];
        bl[j] = *(const short8*)&Bsl[wn * 128 + (jh * 4 + j) * 16 + fi][fq * 8];
      }
      #pragma unroll
      for (int i = 0; i < 4; i++)
        #pragma unroll
        for (int j = 0; j < 4; j++) {
          acc[i][jh * 4 + j] = __builtin_amdgcn_mfma_f32_16x16x32_bf16(ah[i], bh[j], acc[i][jh * 4 + j], 0, 0, 0);
          acc[i][jh * 4 + j] = __builtin_amdgcn_mfma_f32_16x16x32_bf16(ah[i], bl[j], acc[i][jh * 4 + j], 0, 0, 0);
          acc[i][jh * 4 + j] = __builtin_amdgcn_mfma_f32_16x16x32_bf16(al[i], bh[j], acc[i][jh * 4 + j], 0, 0, 0);
        }
    }
    __syncthreads();
  }

  if (mode >= 3) {
    // per-row LN stats across all 256 cols
    #pragma unroll
    for (int i = 0; i < 4; i++)
      #pragma unroll
      for (int reg = 0; reg < 4; reg++) {
        float s = 0.f, q = 0.f;
        #pragma unroll
        for (int j = 0; j < 8; j++) { float v = acc[i][j][reg]; s += v; q += v * v; }
        #pragma unroll
        for (int m = 1; m < 16; m <<= 1) { s += __shfl_xor(s, m, 64); q += __shfl_xor(q, m, 64); }
        if (fi == 0) {
          int row = wm * 64 + i * 16 + fq * 4 + reg;
          lnS[wn][row] = s; lnQ[wn][row] = q;
        }
      }
    __syncthreads();
    if (t < 128) {
      float s = lnS[0][t] + lnS[1][t];
      float q = lnQ[0][t] + lnQ[1][t];
      float m = s * (1.f / 256.f);
      float var = q * (1.f / 256.f) - m * m;
      muS[t] = m; rsS[t] = rsqrtf(var + 1e-5f);
    }
    __syncthreads();
  }

  #pragma unroll
  for (int i = 0; i < 4; i++) {
    #pragma unroll
    for (int reg = 0; reg < 4; reg++) {
      int row = wm * 64 + i * 16 + fq * 4 + reg;
      int gr = row0 + row;
      if (gr >= M || gr >= cntb) continue;
      #pragma unroll
      for (int j = 0; j < 8; j++) {
        int col = wn * 128 + j * 16 + fi;
        float v = acc[i][j][reg];
        if (mode == 2) { v = (v > 0.f) ? (v + 1.f) : expf(v); C[cBase + (long)gr * 256 + col] = v; }
        else if (mode == 3) { C[cBase + (long)gr * 256 + col] = (v - muS[row]) * rsS[row]; }
        else if (mode == 4) { X[xBase + (long)gr * 256 + col] += (v - muS[row]) * rsS[row]; }
        else { C[cBase + (long)gr * 256 + col] = v; }
      }
    }
  }
}

// ---------------------------------------------------------------------------
// fp32-B MFMA GEMM (dmatrix only).
// ---------------------------------------------------------------------------
__global__ __launch_bounds__(256) void gemm_f32b_kernel(
    const float* __restrict__ A, const float* __restrict__ B, float* __restrict__ C,
    int M, int N, int Kd, long sA, long sB, long sC, float alpha)
{
  int b = blockIdx.z;
  const float* Ab = A + (long)b * sA;
  const float* Bb = B + (long)b * sB;
  float* Cb = C + (long)b * sC;
  int row0 = blockIdx.y * 128, col0 = blockIdx.x * 128;
  int t = threadIdx.x;
  int lane = t & 63, wid = t >> 6, wm = wid >> 1, wn = wid & 1;
  int fi = lane & 15, fq = lane >> 4;
  __shared__ __align__(16) short Ah[128][36];
  __shared__ __align__(16) short Al[128][36];
  __shared__ __align__(16) short Bsh[128][36];
  __shared__ __align__(16) short Bsl[128][36];
  f32x4 acc[4][4];
  #pragma unroll
  for (int i = 0; i < 4; i++)
    #pragma unroll
    for (int j = 0; j < 4; j++)
      acc[i][j] = (f32x4){0.f, 0.f, 0.f, 0.f};
  int tr = t >> 3, tc = (t & 7) * 4;
  int bn = (t & 31) * 4, bk = t >> 5;
  for (int k0 = 0; k0 < Kd; k0 += 32) {
    #pragma unroll
    for (int p = 0; p < 4; p++) {
      int r = tr + p * 32, gr = row0 + r;
      float4 v = make_float4(0.f, 0.f, 0.f, 0.f);
      if (gr < M) v = *(const float4*)&Ab[(long)gr * Kd + k0 + tc];
      float vv[4] = {v.x, v.y, v.z, v.w};
      #pragma unroll
      for (int e = 0; e < 4; e++) {
        short h = f2bf(vv[e]); Ah[r][tc + e] = h; Al[r][tc + e] = f2bf(vv[e] - bf2f(h));
      }
    }
    #pragma unroll
    for (int p = 0; p < 4; p++) {
      int kk = bk + p * 8;
      long gkN = (long)(k0 + kk) * N;
      #pragma unroll
      for (int e = 0; e < 4; e++) {
        int gc = col0 + bn + e;
        float v = (gc < N) ? Bb[gkN + gc] : 0.f;
        short h = f2bf(v); Bsh[bn + e][kk] = h; Bsl[bn + e][kk] = f2bf(v - bf2f(h));
      }
    }
    __syncthreads();
    short8 ah[4], al[4], bh[4], bl[4];
    #pragma unroll
    for (int i = 0; i < 4; i++) {
      ah[i] = *(const short8*)&Ah[wm * 64 + i * 16 + fi][fq * 8];
      al[i] = *(const short8*)&Al[wm * 64 + i * 16 + fi][fq * 8];
    }
    #pragma unroll
    for (int j = 0; j < 4; j++) {
      bh[j] = *(const short8*)&Bsh[wn * 64 + j * 16 + fi][fq * 8];
      bl[j] = *(const short8*)&Bsl[wn * 64 + j * 16 + fi][fq * 8];
    }
    #pragma unroll
    for (int i = 0; i < 4; i++)
      #pragma unroll
      for (int j = 0; j < 4; j++) {
        acc[i][j] = __builtin_amdgcn_mfma_f32_16x16x32_bf16(ah[i], bh[j], acc[i][j], 0, 0, 0);
        acc[i][j] = __builtin_amdgcn_mfma_f32_16x16x32_bf16(ah[i], bl[j], acc[i][j], 0, 0, 0);
        acc[i][j] = __builtin_amdgcn_mfma_f32_16x16x32_bf16(al[i], bh[j], acc[i][j], 0, 0, 0);
      }
    __syncthreads();
  }
  #pragma unroll
  for (int i = 0; i < 4; i++) {
    #pragma unroll
    for (int reg = 0; reg < 4; reg++) {
      int gr = row0 + wm * 64 + i * 16 + fq * 4 + reg;
      if (gr >= M) continue;
      #pragma unroll
      for (int j = 0; j < 4; j++) {
        int gc = col0 + wn * 64 + j * 16 + fi;
        if (gc < N) Cb[(long)gr * N + gc] = acc[i][j][reg] * alpha;
      }
    }
  }
}

// ---------------------------------------------------------------------------
__device__ __forceinline__ float2 blk_sum2_256(float a, float b)
{
  __shared__ float sa[4], sb[4];
  int lane = threadIdx.x & 63, w = threadIdx.x >> 6;
  #pragma unroll
  for (int off = 32; off > 0; off >>= 1) { a += __shfl_down(a, off, 64); b += __shfl_down(b, off, 64); }
  if (lane == 0) { sa[w] = a; sb[w] = b; }
  __syncthreads();
  float ra = sa[0] + sa[1] + sa[2] + sa[3];
  float rb = sb[0] + sb[1] + sb[2] + sb[3];
  __syncthreads();
  return make_float2(ra, rb);
}

__global__ void cvt_kernel(float* dst, const float* src, long n) {
  long i = (long)blockIdx.x * 256 + threadIdx.x;
  if (i < n) dst[i] = src[i];
}

__global__ void bcast_seeds_kernel(float* seeds, const float* st) {
  long i = (long)blockIdx.x * 256 + threadIdx.x;
  if (i < 4L * 25600) seeds[i] = st[i % 25600];
}

// KV[s,h,d,e] += sum_r K*V*inv_s ; Ksum[s,h,d] += sum_r K. plain or packed.
__global__ __launch_bounds__(1024) void kv_kernel(
    const float* __restrict__ Kb, const float* __restrict__ Vb,
    float* __restrict__ KV, float* __restrict__ Ksum,
    int s_len, float inv_s, const int* __restrict__ cnt, int bmask, int bxor,
    const int* __restrict__ segOff, const int* __restrict__ segCnt,
    int axor, int gmin, int gmax, int chunk)
{
  int s = blockIdx.x, h = blockIdx.y;
  long srcBase; int slim;
  if (segOff) {
    int g = s & 7;
    if (g < gmin || g > gmax) return;
    int src = s ^ axor;
    srcBase = (long)(src & 7) * ARENA + segOff[src];
    slim = segCnt[src];
  } else {
    int ab = (s & bmask) ^ bxor;
    srcBase = (long)s * s_len;
    slim = cnt ? min(cnt[ab], s_len) : s_len;
  }
  int s0b = blockIdx.z * chunk;
  int send = min(s0b + chunk, slim);
  if (s0b >= send) return;
  __shared__ float Kt[32][33];
  __shared__ float Vt[32][33];
  int tx = threadIdx.x, ty = threadIdx.y;
  float acc = 0.f, ks = 0.f;
  for (int s0 = s0b; s0 < send; s0 += 32) {
    int sr = s0 + ty;
    float kvv = 0.f, vvv = 0.f;
    if (sr < send) {
      long base = (srcBase + sr) * 256 + h * 32 + tx;
      kvv = Kb[base]; vvv = Vb[base];
    }
    Kt[ty][tx] = kvv; Vt[ty][tx] = vvv;
    __syncthreads();
    #pragma unroll
    for (int j = 0; j < 32; j++) acc += Kt[j][ty] * Vt[j][tx];
    if (tx == 0) {
      #pragma unroll
      for (int j = 0; j < 32; j++) ks += Kt[j][ty];
    }
    __syncthreads();
  }
  atomicAdd(&KV[((s * 8 + h) * 32 + ty) * 32 + tx], acc * inv_s);
  if (tx == 0) atomicAdd(&Ksum[s * 256 + h * 32 + ty], ks);
}

// msg = (Q·KV) * Z * s_scale ; Z = 1/(Q·Ksum + 1e-6). plain or packed.
__global__ __launch_bounds__(256) void zmsg_kernel(
    const float* __restrict__ Q, const float* __restrict__ KV,
    const float* __restrict__ Ksum, float* __restrict__ msg, int l, float s_scale,
    const int* __restrict__ cnt,
    const int* __restrict__ segOff, const int* __restrict__ segCnt, int gmin, int gmax)
{
  int s = blockIdx.x;
  long rowBase; int cb;
  if (segOff) {
    int g = s & 7;
    if (g < gmin || g > gmax) return;
    rowBase = (long)g * ARENA + segOff[s];
    cb = segCnt[s];
  } else {
    rowBase = (long)s * l;
    cb = cnt ? min(cnt[s], l) : l;
  }
  int r0 = blockIdx.y * 8;
  if (r0 >= cb) return;
  int t = threadIdx.x;
  __shared__ float KVs[8192];
  __shared__ float QL[256];
  __shared__ float Zl[8];
  for (int i = t; i < 8192; i += 256) KVs[i] = KV[s * 8192 + i];
  float Ks = Ksum[s * 256 + t];
  __syncthreads();
  int h = t >> 5, e = t & 31;
  for (int rr = 0; rr < 8; rr++) {
    int row = r0 + rr;
    if (row >= cb) break;
    long base = (rowBase + row) * 256;
    QL[t] = Q[base + t];
    __syncthreads();
    float p = QL[t] * Ks;
    #pragma unroll
    for (int off = 16; off > 0; off >>= 1) p += __shfl_down(p, off, 32);
    if (e == 0) Zl[h] = 1.f / (p + 1e-6f);
    __syncthreads();
    float acc = 0.f;
    const float* kvh = KVs + h * 1024;
    #pragma unroll
    for (int d = 0; d < 32; d++) acc += QL[h * 32 + d] * kvh[d * 32 + e];
    msg[base + t] = acc * Zl[h] * s_scale;
    __syncthreads();
  }
}

// ---------------- topic pipeline ----------------
__global__ void tm_build_kernel(const float* t0, const float* t1, float* tm) {
  int n = blockIdx.x, m = blockIdx.y, l = threadIdx.x;
  if (l >= 100) return;
  float acc = 0.f;
  for (int d = 0; d < 96; d++)
    acc += t0[(n * 96 + d) * 100 + m] * t1[(n * 96 + d) * 100 + l];
  tm[(n * 100 + m) * 100 + l] = floorf(acc * 0.0625f);
}

__global__ void tm_colstats_kernel(const float* tm, float* cmax, float* csum) {
  int n = blockIdx.x, l = blockIdx.y, t = threadIdx.x;
  __shared__ float red[128];
  float v = (t < 100) ? tm[(n * 100 + t) * 100 + l] : -1e30f;
  red[t] = v; __syncthreads();
  for (int off = 64; off > 0; off >>= 1) { if (t < off) red[t] = fmaxf(red[t], red[t + off]); __syncthreads(); }
  float mx = red[0]; __syncthreads();
  float e = (t < 100) ? expf(v - mx) : 0.f;
  red[t] = e; __syncthreads();
  for (int off = 64; off > 0; off >>= 1) { if (t < off) red[t] += red[t + off]; __syncthreads(); }
  if (t == 0) { cmax[n * 100 + l] = mx; csum[n * 100 + l] = red[0]; }
}

__global__ void tm_rowstats_kernel(const float* tm, float* rmax, float* rsum) {
  int n = blockIdx.x, m = blockIdx.y, t = threadIdx.x;
  __shared__ float red[128];
  float v = (t < 100) ? tm[(n * 100 + m) * 100 + t] : -1e30f;
  red[t] = v; __syncthreads();
  for (int off = 64; off > 0; off >>= 1) { if (t < off) red[t] = fmaxf(red[t], red[t + off]); __syncthreads(); }
  float mx = red[0]; __syncthreads();
  float e = (t < 100) ? expf(v - mx) : 0.f;
  red[t] = e; __syncthreads();
  for (int off = 64; off > 0; off >>= 1) { if (t < off) red[t] += red[t + off]; __syncthreads(); }
  if (t == 0) { rmax[n * 100 + m] = mx; rsum[n * 100 + m] = red[0]; }
}

__global__ void tm_argmax_kernel(const float* tm, const float* cmax, const float* csum,
                                 const float* rmax, const float* rsum, int* tmidx) {
  int n = blockIdx.x, m = blockIdx.y, t = threadIdx.x;
  __shared__ float rv[128]; __shared__ int ri[128];
  float v = -1e30f;
  if (t < 100) {
    float x = tm[(n * 100 + m) * 100 + t];
    v = (expf(x - cmax[n * 100 + t]) / csum[n * 100 + t]) * (expf(x - rmax[n * 100 + m]) / rsum[n * 100 + m]);
  }
  rv[t] = v; ri[t] = t; __syncthreads();
  for (int off = 64; off > 0; off >>= 1) {
    if (t < off) {
      if (rv[t + off] > rv[t] || (rv[t + off] == rv[t] && ri[t + off] < ri[t])) { rv[t] = rv[t + off]; ri[t] = ri[t + off]; }
    }
    __syncthreads();
  }
  if (t == 0) tmidx[n * 100 + m] = ri[0];
}

__global__ void topicp_kernel(const float* t0raw, const float* t1raw, const int* tmidx, float* topicp) {
  int n = blockIdx.x, m = blockIdx.y, j = threadIdx.x;
  if (j >= 96) return;
  int g = tmidx[300 + m];
  float a, b;
  if (j < 48) {
    a = t0raw[(n * 96 + 2 * j) * 100 + m];
    b = t0raw[(n * 96 + 2 * j + 1) * 100 + m];
  } else {
    int d0 = 2 * j - 96;
    a = t1raw[(n * 96 + d0) * 100 + g];
    b = t1raw[(n * 96 + d0 + 1) * 100 + g];
  }
  topicp[(n * 100 + m) * 96 + j] = 0.5f * (a + b);
}

__global__ void seedsF_kernel(const float* seeds, const float* topicp, float* seedsF) {
  int n = blockIdx.x, k = blockIdx.y, t = threadIdx.x;
  float v;
  if (t < 160) {
    int s = (t * 256) / 160;
    int e = ((t + 1) * 256 + 159) / 160;
    float a = 0.f;
    for (int i = s; i < e; i++) a += seeds[(n * 100 + k) * 256 + i];
    v = a / (float)(e - s);
  } else {
    v = topicp[(n * 100 + k) * 96 + (t - 160)];
  }
  float2 r = blk_sum2_256(v, v * v);
  float m = r.x * (1.f / 256.f);
  float var = r.y * (1.f / 256.f) - m * m;
  seedsF[(n * 100 + k) * 256 + t] = (v - m) * rsqrtf(var + 1e-5f);
}

__global__ void transpose_seeds_kernel(const float* sF, float* sT) {
  long i = (long)blockIdx.x * 256 + threadIdx.x;
  if (i >= 4L * 25600) return;
  int n = (int)(i / 25600); int r = (int)(i % 25600); int k = r / 256; int d = r % 256;
  sT[n * 25600 + d * 100 + k] = sF[i];
}

// ---------------- dmatrix post ----------------
__global__ void softmax_rows_kernel(const float* dm, float* prob) {
  long row = blockIdx.x; int t = threadIdx.x;
  __shared__ float red[128];
  float v = (t < 100) ? dm[row * 100 + t] : -1e30f;
  red[t] = v; __syncthreads();
  for (int off = 64; off > 0; off >>= 1) { if (t < off) red[t] = fmaxf(red[t], red[t + off]); __syncthreads(); }
  float mx = red[0]; __syncthreads();
  float e = (t < 100) ? expf(v - mx) : 0.f;
  red[t] = e; __syncthreads();
  for (int off = 64; off > 0; off >>= 1) { if (t < off) red[t] += red[t + off]; __syncthreads(); }
  float s = red[0];
  if (t < 100) prob[row * 100 + t] = e / s;
}

__global__ void colsum_kernel(const float* prob, float* cs0, float* cs1) {
  int k = blockIdx.x, n = blockIdx.y, half = blockIdx.z;
  int t = threadIdx.x;
  const float* p = prob + ((long)n * 8192 + half * 4096) * 100 + k;
  float s = 0.f;
  for (int m = t; m < 4096; m += 256) s += p[(long)m * 100];
  float2 r = blk_sum2_256(s, 0.f);
  if (t == 0) (half ? cs1 : cs0)[n * 100 + k] = r.x;
}

__global__ void topk_kernel(const float* cs0, const float* cs1, int* inds) {
  int n = blockIdx.x, t = threadIdx.x;
  __shared__ float rv[128]; __shared__ int ri[128]; __shared__ int sbest;
  float base = (t < 100) ? cs0[n * 100 + t] * cs1[n * 100 + t] : -1.f;
  for (int kk = 0; kk < 6; kk++) {
    rv[t] = base; ri[t] = t; __syncthreads();
    for (int off = 64; off > 0; off >>= 1) {
      if (t < off) {
        if (rv[t + off] > rv[t] || (rv[t + off] == rv[t] && ri[t + off] < ri[t])) { rv[t] = rv[t + off]; ri[t] = ri[t + off]; }
      }
      __syncthreads();
    }
    if (t == 0) { inds[n * 6 + kk] = ri[0]; sbest = ri[0]; }
    __syncthreads();
    if (t == sbest) base = -1.f;
    __syncthreads();
  }
}

__global__ void argmax_rows_kernel(const float* dm, int* amax) {
  int row = blockIdx.x * 256 + threadIdx.x;
  if (row >= 32768) return;
  const float* p = dm + (long)row * 100;
  float best = p[0]; int bi = 0;
  for (int k = 1; k < 100; k++) { float v = p[k]; if (v > best) { best = v; bi = k; } }
  amax[row] = bi;
}

// ---------------- packed sample machinery ----------------
__global__ __launch_bounds__(1024) void count_kernel(const int* amax, const int* inds, int* segCnt) {
  int seg = blockIdx.x;
  int kk = seg >> 3, g = seg & 7, n = g & 3, half = g >> 2;
  int target = inds[n * 6 + kk];
  const int* am = amax + n * 8192 + half * 4096;
  int t = threadIdx.x;
  int lc = 0;
  #pragma unroll
  for (int j = 0; j < 4; j++) lc += (am[t * 4 + j] == target) ? 1 : 0;
  __shared__ int red[16];
  #pragma unroll
  for (int off = 32; off > 0; off >>= 1) lc += __shfl_down(lc, off, 64);
  if ((t & 63) == 0) red[t >> 6] = lc;
  __syncthreads();
  if (t == 0) {
    int s = 0;
    for (int w = 0; w < 16; w++) s += red[w];
    segCnt[seg] = s;
  }
}

__global__ void offs_kernel(const int* segCnt, int* segOff, float* condf) {
  int t = threadIdx.x;
  if (t < 8) {
    int run = 0;
    for (int kk = 0; kk < 6; kk++) {
      segOff[kk * 8 + t] = run;
      run += (segCnt[kk * 8 + t] + 127) & ~127;
    }
  }
  if (t >= 8 && t < 14) {
    int kk = t - 8;
    int a = 0, b = 0;
    for (int g = 0; g < 4; g++) { a += segCnt[kk * 8 + g]; b += segCnt[kk * 8 + 4 + g]; }
    condf[kk] = (a > 0 && b > 0) ? 1.f : 0.f;
  }
}

__global__ __launch_bounds__(1024) void ord_kernel(const int* amax, const int* inds,
                                                   const int* segOff, int* ordP) {
  int seg = blockIdx.x;
  int kk = seg >> 3, g = seg & 7, n = g & 3, half = g >> 2;
  int target = inds[n * 6 + kk];
  const int* am = amax + n * 8192 + half * 4096;
  int t = threadIdx.x;
  __shared__ int ts[1024];
  int f[4]; int lc = 0;
  #pragma unroll
  for (int j = 0; j < 4; j++) { f[j] = (am[t * 4 + j] == target) ? 1 : 0; lc += f[j]; }
  ts[t] = lc; __syncthreads();
  for (int off = 1; off < 1024; off <<= 1) {
    int add = (t >= off) ? ts[t - off] : 0;
    __syncthreads();
    ts[t] += add;
    __syncthreads();
  }
  int run = (t == 0) ? 0 : ts[t - 1];
  int* o = ordP + ((long)g * ARENA + segOff[seg]);
  #pragma unroll
  for (int j = 0; j < 4; j++) {
    if (f[j]) { o[run] = t * 4 + j; run++; }
  }
}

__global__ void gather_kernel(float* nf, const float* f01, const int* ordP,
                              const int* segOff, const int* segCnt) {
  int seg = blockIdx.y;
  int g = seg & 7;
  int cntb = segCnt[seg];
  int row0 = blockIdx.x * 128;
  if (row0 >= cntb) return;
  long base = (long)g * ARENA + segOff[seg];
  int t = threadIdx.x;
  int c4 = (t & 63) * 4, rr = t >> 6;
  for (int p = 0; p < 32; p++) {
    int r = row0 + p * 4 + rr;
    if (r >= cntb) break;
    int tok = ordP[base + r];
    *(float4*)&nf[(base + r) * 256 + c4] =
        *(const float4*)&f01[((long)g * 4096 + tok) * 256 + c4];
  }
}

__global__ void scatter_kernel(float* up, const float* nf, const int* ordP,
                               const int* segOff, const int* segCnt, const float* condf) {
  int seg = blockIdx.y;
  int kk = seg >> 3, g = seg & 7;
  int cntb = segCnt[seg];
  int row0 = blockIdx.x * 128;
  if (row0 >= cntb) return;
  long base = (long)g * ARENA + segOff[seg];
  float cf = condf[kk];
  int t = threadIdx.x;
  int c4 = (t & 63) * 4, rr = t >> 6;
  for (int p = 0; p < 32; p++) {
    int r = row0 + p * 4 + rr;
    if (r >= cntb) break;
    int tok = ordP[base + r];
    float4 add = *(const float4*)&nf[(base + r) * 256 + c4];
    float4* dst = (float4*)&up[((long)g * 4096 + tok) * 256 + c4];
    float4 cur = *dst;
    cur.x += add.x * cf; cur.y += add.y * cf; cur.z += add.z * cf; cur.w += add.w * cf;
    *dst = cur;
  }
}

// up01 aliases out's feat region (index-identical); in-place RMW.
__global__ void final_mix_kernel(const float* f01, float* out_up, const int* amax,
                                 const int* inds) {
  int b = blockIdx.y, half = b >> 2, n = b & 3;
  int l = blockIdx.x, c = threadIdx.x;
  int a = amax[n * 8192 + half * 4096 + l];
  const int* in_ = inds + n * 6;
  bool member = (a == in_[0]) | (a == in_[1]) | (a == in_[2]) | (a == in_[3]) | (a == in_[4]) | (a == in_[5]);
  long idx = ((long)b * 4096 + l) * 256 + c;
  float up = out_up[idx];
  out_up[idx] = (member ? 0.f : 1.f) * f01[idx] + up;
}

__global__ void tmi_kernel(const float* dmat, float* out) {
  int n = blockIdx.y, half = blockIdx.z;
  long i = (long)blockIdx.x * 256 + threadIdx.x;
  const float* dm = dmat + (long)n * 819200 + (long)half * 409600;
  int a = (int)(i / 100), b = (int)(i % 100);
  int y = a >> 6, x = a & 63;
  float sum = 0.f;
  for (int dy = -1; dy <= 1; dy++) {
    int yy = y + dy; if (yy < 0 || yy >= 64) continue;
    for (int dx = -1; dx <= 1; dx++) {
      int xc = x + dx; if (xc < 0 || xc >= 64) continue;
      sum += dm[b * 4096 + yy * 64 + xc];
    }
  }
  out[8388608L + (long)half * 1638400 + (long)n * 409600 + i] = dm[i] * (sum * (1.f / 9.f));
}

// ---------------------------------------------------------------------------
extern "C" void kernel_launch(void* const* d_in, const int* in_sizes, int n_in,
                              void* d_out, int out_size, void* d_ws, size_t ws_size,
                              hipStream_t stream)
{
  (void)in_sizes; (void)n_in; (void)out_size; (void)ws_size;
  const float* feat0_in = (const float*)d_in[0];
  const float* feat1_in = (const float*)d_in[1];
  const float* topic0 = (const float*)d_in[2];
  const float* topic1 = (const float*)d_in[3];
  const float* seed_tokens = (const float*)d_in[4];
  const float* Wq = (const float*)d_in[5];
  const float* Wk = (const float*)d_in[6];
  const float* Wv = (const float*)d_in[7];
  const float* Wm = (const float*)d_in[8];
  const float* W1 = (const float*)d_in[9];
  const float* W2 = (const float*)d_in[10];
  float* out = (float*)d_out;

  float* base = (float*)d_ws;
  long off = 0;
  auto alloc = [&](long n) -> float* { float* p = base + off; off += (n + 255) & ~255L; return p; };
  float* f01   = alloc(8388608);          // [8][4096][256]
  float* qb    = alloc(8L * ARENA * 256); // Q / LN(msg2)
  float* kb    = alloc(8L * ARENA * 256); // K / msg / h1 low   (kb,vb contiguous)
  float* vb    = alloc(8L * ARENA * 256); // V / h1 high
  float* nf    = alloc(8L * ARENA * 256); // packed sample tokens
  float* seeds = alloc(102400);
  float* kvks  = alloc(48 * 8192 + 48 * 256);
  float* dmat  = alloc(3276800);
  short* wbuf  = (short*)alloc(5242880);
  float* tmb   = alloc(40000);
  float* cmaxb = alloc(400); float* csumb = alloc(400);
  float* rmaxb = alloc(400); float* rsumb = alloc(400);
  float* topicp= alloc(38400);
  float* sF    = alloc(102400);
  float* sT    = alloc(102400);
  float* cs0   = alloc(400);
  float* cs1   = alloc(400);
  float* condf = alloc(256);
  int* tmidx  = (int*)alloc(400);
  int* amax   = (int*)alloc(32768);
  int* inds   = (int*)alloc(256);
  int* segCnt = (int*)alloc(256);
  int* segOffA= (int*)alloc(256);
  int* ordP   = (int*)alloc(8L * ARENA);
  float* up01 = out;                      // aliases out's feat region

  auto WOFF = [](int l) -> long { return (long)l * 1310720; };

  auto gmain = [&](const float* A, const float* A2, int aw, long wOff, int loD,
                   float* c0, float* c1, float* c2, int M, int Kd, int Ntot, int outW,
                   long sA_, long sC_, int bm, int bx,
                   const int* sOff, int gmin, int gmax,
                   int m0, int m1, int m2_, int nb) {
    dim3 g(Ntot / 128, (M + 127) / 128, nb), blk(256);
    gemm_main_kernel<<<g, blk, 0, stream>>>(A, A2, aw, wbuf + wOff, loD, c0, c1, c2,
        M, Kd, outW, sA_, sC_, nullptr, bm, bx, sOff, sOff ? segCnt : nullptr, gmin, gmax, m0, m1, m2_);
  };
  auto g256 = [&](const float* A, int aw, long wOff, int loD, float* C, float* X,
                  int M, int Kd, long sA_, long sC_, long sX_, int bm, int bx,
                  const int* sOff, int gmin, int gmax, int mode, int nb) {
    dim3 g(1, (M + 127) / 128, nb), blk(256);
    gemm256_kernel<<<g, blk, 0, stream>>>(A, aw, wbuf + wOff, loD, C, X,
        M, Kd, sA_, sC_, sX_, nullptr, bm, bx, sOff, sOff ? segCnt : nullptr, gmin, gmax, mode);
  };
  // encTail: Q in qb, K in kb, V in vb already. kv -> zmsg(msg->kb) ->
  // msg2+LN -> qb -> h1 -> kbvb[row][512] -> h2+addLN -> x
  auto encTail = [&](float* x, int l, int s_len, float s_scale, int layer, int nb,
                     long sAx, const int* sOff, int gmin, int gmax, int axor, int bmKV, int bxKV) {
    hipMemsetAsync(kvks, 0, (48 * 8192 + 48 * 256) * sizeof(float), stream);
    int nch = (s_len + 1023) / 1024;
    kv_kernel<<<dim3(nb, 8, nch), dim3(32, 32), 0, stream>>>(
        kb, vb, kvks, kvks + 48 * 8192, s_len, 1.f / s_scale, nullptr, bmKV, bxKV,
        sOff, sOff ? segCnt : nullptr, axor, gmin, gmax, 1024);
    zmsg_kernel<<<dim3(nb, (l + 7) / 8), 256, 0, stream>>>(
        qb, kvks, kvks + 48 * 8192, kb, l, s_scale, nullptr,
        sOff, sOff ? segCnt : nullptr, gmin, gmax);
    g256(kb, 256, WOFF(layer) + 393216, 65536, qb, nullptr,
         l, 256, sAx, sAx, 0, 7, 0, sOff, gmin, gmax, 3, nb);
    gmain(x, qb, 256, WOFF(layer) + 524288, 262144, kb, nullptr, nullptr,
          l, 512, 512, 512, sAx, sAx * 2, 7, 0, sOff, gmin, gmax, 1, 0, 0, nb);
    g256(kb, 512, WOFF(layer) + 1048576, 131072, nullptr, x,
         l, 512, sAx * 2, 0, sAx, 7, 0, sOff, gmin, gmax, 4, nb);
  };

  // ---- init ----
  cvt_kernel<<<16384, 256, 0, stream>>>(f01, feat0_in, 4194304);
  cvt_kernel<<<16384, 256, 0, stream>>>(f01 + 4194304, feat1_in, 4194304);
  bcast_seeds_kernel<<<400, 256, 0, stream>>>(seeds, seed_tokens);
  prep_w_kernel<<<20480, 256, 0, stream>>>(Wq, Wk, Wv, Wm, W1, W2, wbuf);

  // ---- topic pipeline ----
  tm_build_kernel<<<dim3(4, 100), 128, 0, stream>>>(topic0, topic1, tmb);
  tm_colstats_kernel<<<dim3(4, 100), 128, 0, stream>>>(tmb, cmaxb, csumb);
  tm_rowstats_kernel<<<dim3(4, 100), 128, 0, stream>>>(tmb, rmaxb, rsumb);
  tm_argmax_kernel<<<dim3(4, 100), 128, 0, stream>>>(tmb, cmaxb, csumb, rmaxb, rsumb, tmidx);
  topicp_kernel<<<dim3(4, 100), 128, 0, stream>>>(topic0, topic1, tmidx, topicp);

  // ---- main encoder layers ----
  auto encSeedLayer = [&](int layer) {
    g256(seeds, 256, WOFF(layer), 196608, qb, nullptr,
         100, 256, 25600, 25600, 0, 7, 0, nullptr, 0, 7, 2, 4);
    gmain(feat0_in, nullptr, 256, WOFF(layer) + 65536, 196608, kb, vb, nullptr,
          4096, 256, 512, 256, 1048576, 2097152, 7, 0, nullptr, 0, 7, 2, 0, 0, 4);
    gmain(feat1_in, nullptr, 256, WOFF(layer) + 65536, 196608, kb + 1048576, vb + 1048576, nullptr,
          4096, 256, 512, 256, 1048576, 2097152, 7, 0, nullptr, 0, 7, 2, 0, 0, 4);
    encTail(seeds, 100, 8192, 8192.f, layer, 4, 25600, nullptr, 0, 7, 0, 7, 0);
  };
  auto encFeatLayer = [&](int layer) {
    g256(f01, 256, WOFF(layer), 196608, qb, nullptr,
         4096, 256, 1048576, 1048576, 0, 7, 0, nullptr, 0, 7, 2, 8);
    gmain(seeds, nullptr, 256, WOFF(layer) + 65536, 196608, kb, vb, nullptr,
          100, 256, 512, 256, 25600, 25600, 3, 0, nullptr, 0, 7, 2, 0, 0, 8);
    encTail(f01, 4096, 100, 100.f, layer, 8, 1048576, nullptr, 0, 7, 0, 7, 0);
  };

  encSeedLayer(0);
  encFeatLayer(1);
  encSeedLayer(2);
  encFeatLayer(3);

  // ---- seeds final + dmatrix ----
  seedsF_kernel<<<dim3(4, 100), 256, 0, stream>>>(seeds, topicp, sF);
  transpose_seeds_kernel<<<400, 256, 0, stream>>>(sF, sT);
  {
    dim3 g(1, 32, 4), blk(256);
    gemm_f32b_kernel<<<g, blk, 0, stream>>>(feat0_in, sT, dmat, 4096, 100, 256, 1048576, 25600, 819200, 0.0625f);
    gemm_f32b_kernel<<<g, blk, 0, stream>>>(feat1_in, sT, dmat + 409600, 4096, 100, 256, 1048576, 25600, 819200, 0.0625f);
  }
  float* prob = kb;
  softmax_rows_kernel<<<32768, 128, 0, stream>>>(dmat, prob);
  colsum_kernel<<<dim3(100, 4, 2), 256, 0, stream>>>(prob, cs0, cs1);
  topk_kernel<<<4, 128, 0, stream>>>(cs0, cs1, inds);
  argmax_rows_kernel<<<128, 256, 0, stream>>>(dmat, amax);

  hipMemsetAsync(up01, 0, 8388608 * sizeof(float), stream);

  // ---- sample phase: all 6 samples x 8 halves packed into 48 segments ----
  count_kernel<<<48, 1024, 0, stream>>>(amax, inds, segCnt);
  offs_kernel<<<1, 64, 0, stream>>>(segCnt, segOffA, condf);
  ord_kernel<<<48, 1024, 0, stream>>>(amax, inds, segOffA, ordP);
  gather_kernel<<<dim3(32, 48), 256, 0, stream>>>(nf, f01, ordP, segOffA, segCnt);

  for (int idt = 0; idt < 2; idt++) {
    int wA = 4 + idt * 2, wB = wA + 1;
    // wA: self-attention, all 48 segments
    gmain(nf, nullptr, 256, WOFF(wA), 196608, qb, kb, vb,
          4096, 256, 768, 256, 0, 0, 0, 0, segOffA, 0, 7, 2, 2, 0, 48);
    encTail(nf, 4096, 4096, 4096.f, wA, 48, 0, segOffA, 0, 7, 0, 0, 0);
    // wB step 1: x = g0..3, source = g4..7
    g256(nf, 256, WOFF(wB), 196608, qb, nullptr,
         4096, 256, 0, 0, 0, 0, 0, segOffA, 0, 3, 2, 48);
    gmain(nf, nullptr, 256, WOFF(wB) + 65536, 196608, kb, vb, nullptr,
          4096, 256, 512, 256, 0, 0, 0, 0, segOffA, 4, 7, 2, 0, 0, 48);
    encTail(nf, 4096, 4096, 4096.f, wB, 48, 0, segOffA, 0, 3, 4, 0, 0);
    // wB step 2: x = g4..7, source = UPDATED g0..3
    g256(nf, 256, WOFF(wB), 196608, qb, nullptr,
         4096, 256, 0, 0, 0, 0, 0, segOffA, 4, 7, 2, 48);
    gmain(nf, nullptr, 256, WOFF(wB) + 65536, 196608, kb, vb, nullptr,
          4096, 256, 512, 256, 0, 0, 0, 0, segOffA, 0, 3, 2, 0, 0, 48);
    encTail(nf, 4096, 4096, 4096.f, wB, 48, 0, segOffA, 4, 7, 4, 0, 0);
  }
  scatter_kernel<<<dim3(32, 48), 256, 0, stream>>>(up01, nf, ordP, segOffA, segCnt, condf);

  // ---- outputs ----
  final_mix_kernel<<<dim3(4096, 8), 256, 0, stream>>>(f01, up01, amax, inds);
  tmi_kernel<<<dim3(1600, 4, 2), 256, 0, stream>>>(dmat, out);
}